// Round 2
// baseline (419.516 us; speedup 1.0000x reference)
//
#include <hip/hip_runtime.h>
#include <math.h>

#define SDE_B 16384
#define SDE_S 16
#define SDE_STEPS 50
#define SDE_L 128
#define SDE_DT 0.02f
#define SDE_SQRT_DT 0.14142135623730951f
#define SDE_TEMP 20.0f
#define LOG2E 1.44269504088896340736f
#define LN2 0.69314718055994530942f

#if __has_builtin(__builtin_amdgcn_exp2f)
__device__ __forceinline__ float fexp2(float x) { return __builtin_amdgcn_exp2f(x); }
#else
__device__ __forceinline__ float fexp2(float x) { return __exp2f(x); }
#endif

#if __has_builtin(__builtin_amdgcn_logf)
__device__ __forceinline__ float flog2(float x) { return __builtin_amdgcn_logf(x); }
#else
__device__ __forceinline__ float flog2(float x) { return __log2f(x); }
#endif

#if __has_builtin(__builtin_amdgcn_rcpf)
__device__ __forceinline__ float frcp(float x) { return __builtin_amdgcn_rcpf(x); }
#else
__device__ __forceinline__ float frcp(float x) { return 1.0f / x; }
#endif

// stable softplus: max(y,0) + log(1+exp(-|y|))   (setup + once-per-step only)
__device__ __forceinline__ float softplus_fast(float y) {
    float m = fmaxf(y, 0.0f);
    float e = fexp2(-fabsf(y) * LOG2E);
    return fmaf(LN2, flog2(1.0f + e), m);
}

__device__ __forceinline__ float sigmoid_fast(float y) {
    return frcp(1.0f + fexp2(-y * LOG2E));
}

// sum over the 4-lane quad (lanes grouped as sim*4+q) via DPP quad_perm
__device__ __forceinline__ float quad_sum(float v) {
#if __has_builtin(__builtin_amdgcn_mov_dpp)
    int i = __float_as_int(v);
    v += __int_as_float(__builtin_amdgcn_mov_dpp(i, 0xB1, 0xF, 0xF, true)); // xor 1
    i = __float_as_int(v);
    v += __int_as_float(__builtin_amdgcn_mov_dpp(i, 0x4E, 0xF, 0xF, true)); // xor 2
    return v;
#else
    v += __shfl_xor(v, 1, 64);
    v += __shfl_xor(v, 2, 64);
    return v;
#endif
}

__device__ __forceinline__ float fixnum(float v) {
    if (isnan(v)) return 0.0f;
    if (isinf(v)) return v > 0.0f ? 3.4028234663852886e38f : -3.4028234663852886e38f;
    return v;
}

// One wave per batch element b. 64 lanes = 16 sims x 4 hidden-quarters.
// lane = s*4 + q: lane handles sim s, hidden units j = 4*i + q, i in [0,16).
// zw[16] lives in VGPRs; per-unit weights come from LDS float4 (broadcast,
// conflict-free: quad reads 4 consecutive 16B rows).
__global__ void __launch_bounds__(256) sde_kernel(
    const float* __restrict__ z,  const float* __restrict__ W1,
    const float* __restrict__ b1, const float* __restrict__ W2,
    const float* __restrict__ b2, const float* __restrict__ Wb,
    const float* __restrict__ bb, const float* __restrict__ Wn,
    const float* __restrict__ bn, const float* __restrict__ osc,
    const float* __restrict__ obias, const float* __restrict__ noise,
    float* __restrict__ out)
{
    __shared__ float w1s[64 * 131];   // stride 131: kills stride-130 4-way conflicts
    __shared__ float4 wpack[64];      // {W1[j][0], W1[j][1], W2[0][j], W2[1][j]}

    for (int idx = threadIdx.x; idx < 64 * 130; idx += 256) {
        int row = idx / 130, col = idx - row * 130;
        w1s[row * 131 + col] = W1[idx];
    }
    if (threadIdx.x < 64) {
        int j = threadIdx.x;
        wpack[j] = make_float4(W1[j * 130 + 0], W1[j * 130 + 1], W2[j], W2[64 + j]);
    }
    __syncthreads();

    const int lane = threadIdx.x & 63;
    const int wv = threadIdx.x >> 6;
    const int b = blockIdx.x * 4 + wv;
    if (b >= SDE_B) return;
    const int s = lane >> 2;
    const int q = lane & 3;

    const float* zr = z + (size_t)b * SDE_L;

    // --- setup: lane `l` computes zW1 entry for hidden unit j = l ---
    float accz = b1[lane];
    #pragma unroll
    for (int m = 0; m < SDE_L; m += 4) {
        float z0 = zr[m], z1 = zr[m + 1], z2 = zr[m + 2], z3 = zr[m + 3];
        const float* wrow = &w1s[lane * 131 + 2 + m];
        accz = fmaf(z0, wrow[0], accz);
        accz = fmaf(z1, wrow[1], accz);
        accz = fmaf(z2, wrow[2], accz);
        accz = fmaf(z3, wrow[3], accz);
    }

    // --- boundary / ndt: 128-dot reduced over the wave ---
    float zb0 = zr[2 * lane], zb1 = zr[2 * lane + 1];
    float pb = fmaf(zb0, Wb[2 * lane], zb1 * Wb[2 * lane + 1]);
    float pn = fmaf(zb0, Wn[2 * lane], zb1 * Wn[2 * lane + 1]);
    #pragma unroll
    for (int off = 32; off > 0; off >>= 1) {
        pb += __shfl_xor(pb, off, 64);
        pn += __shfl_xor(pn, off, 64);
    }
    const float half_b = 0.5f * (softplus_fast(pb + bb[0]) + 0.3f);
    const float ndt = softplus_fast(pn + bn[0]) + 0.05f;

    // --- redistribute zW1: this lane's 16 hidden units are j = 4i + q ---
    float zw[16];
    #pragma unroll
    for (int i = 0; i < 16; ++i) zw[i] = __shfl(accz, 4 * i + q, 64);

    const float b20 = b2[0], b21 = b2[1];
    const float* nzp = noise + (size_t)b * SDE_S + s;

    float x = 0.0f, surv = 1.0f, ert = 0.0f, ecorr = 0.0f;

    for (int k = 0; k < SDE_STEPS; ++k) {
        float nz = nzp[(size_t)k * (SDE_B * SDE_S)];
        float t = (float)k * SDE_DT;
        float a0 = 0.0f, a1 = 0.0f;
        #pragma unroll
        for (int ig = 0; ig < 4; ++ig) {
            float num[4], den[4], w2a[4], w2b[4];
            #pragma unroll
            for (int u = 0; u < 4; ++u) {
                int i = ig * 4 + u;
                float4 w = wpack[4 * i + q];          // ds_read_b128, broadcast
                float pre = fmaf(x, w.x, fmaf(t, w.y, zw[i]));
                // Pade [5/4] tanh, input clamped to +-3.8 (max err ~1.4e-3)
                float pc = fminf(fmaxf(pre, -3.8f), 3.8f);
                float tt = pc * pc;
                num[u] = pc * fmaf(tt, tt + 105.0f, 945.0f);
                den[u] = fmaf(tt, fmaf(tt, 15.0f, 420.0f), 945.0f);
                w2a[u] = w.z;
                w2b[u] = w.w;
            }
            // one rcp serves 4 divisions
            float p01 = den[0] * den[1], p23 = den[2] * den[3];
            float r = frcp(p01 * p23);
            float r01 = r * p23, r23 = r * p01;
            float h0 = num[0] * (r01 * den[1]);
            float h1 = num[1] * (r01 * den[0]);
            float h2 = num[2] * (r23 * den[3]);
            float h3 = num[3] * (r23 * den[2]);
            a0 = fmaf(h0, w2a[0], fmaf(h1, w2a[1], fmaf(h2, w2a[2], fmaf(h3, w2a[3], a0))));
            a1 = fmaf(h0, w2b[0], fmaf(h1, w2b[1], fmaf(h2, w2b[2], fmaf(h3, w2b[3], a1))));
        }
        a0 = quad_sum(a0);
        a1 = quad_sum(a1);
        // identical on all 4 lanes of the quad -> state stays consistent
        float drift = fminf(fmaxf(a0 + b20, -5.0f), 5.0f);
        float diff = softplus_fast(a1 + b21) + 0.1f;
        x = fmaf(drift, SDE_DT, fmaf(diff * SDE_SQRT_DT, nz, x));
        x = fminf(fmaxf(x, -10.0f), 10.0f);
        float dist = fabsf(x) - half_b;
        float hz = fminf(sigmoid_fast(SDE_TEMP * dist), 0.99f);
        float cross = surv * hz;
        surv = surv * (1.0f - hz);      // == exp(sum log1p(-hz)) to fp32 rounding
        float tn = (float)(k + 1) * SDE_DT;
        ert = fmaf(cross, tn, ert);
        ecorr += (x > 0.0f) ? cross : 0.0f;
    }

    ert += surv;                    // * (STEPS*DT) = 1.0
    ecorr = fmaf(surv, 0.5f, ecorr);
    float rt = ert + ndt;           // seconds; x1000 applied after stats

    // --- stats over 16 sims (mask quad-redundant copies to q==0) ---
    float sr = (q == 0) ? rt : 0.0f;
    float scr = (q == 0) ? ecorr : 0.0f;
    #pragma unroll
    for (int off = 32; off > 0; off >>= 1) {
        sr += __shfl_xor(sr, off, 64);
        scr += __shfl_xor(scr, off, 64);
    }
    float mean = sr * (1.0f / 16.0f);
    float d = rt - mean;
    float vv = (q == 0) ? d * d : 0.0f;
    #pragma unroll
    for (int off = 32; off > 0; off >>= 1) vv += __shfl_xor(vv, off, 64);

    if (lane == 0) {
        float std_ms = sqrtf(vv * (1.0f / 15.0f)) * 1000.0f + 0.001f;
        float o0 = fmaf(mean * 1000.0f, osc[0], obias[0]);
        float o1 = fmaf(std_ms, osc[1], obias[1]);
        float o2 = fmaf(scr * (1.0f / 16.0f), osc[2], obias[2]);
        out[b * 3 + 0] = fixnum(o0);
        out[b * 3 + 1] = fixnum(o1);
        out[b * 3 + 2] = fixnum(o2);
    }
}

extern "C" void kernel_launch(void* const* d_in, const int* in_sizes, int n_in,
                              void* d_out, int out_size, void* d_ws, size_t ws_size,
                              hipStream_t stream) {
    const float* z     = (const float*)d_in[0];
    const float* W1    = (const float*)d_in[1];
    const float* b1    = (const float*)d_in[2];
    const float* W2    = (const float*)d_in[3];
    const float* b2    = (const float*)d_in[4];
    const float* Wb    = (const float*)d_in[5];
    const float* bb    = (const float*)d_in[6];
    const float* Wn    = (const float*)d_in[7];
    const float* bn    = (const float*)d_in[8];
    const float* osc   = (const float*)d_in[9];
    const float* obias = (const float*)d_in[10];
    const float* noise = (const float*)d_in[11];
    float* out = (float*)d_out;

    dim3 grid(SDE_B / 4), block(256);
    sde_kernel<<<grid, block, 0, stream>>>(z, W1, b1, W2, b2, Wb, bb, Wn, bn,
                                           osc, obias, noise, out);
}

// Round 3
// 380.606 us; speedup vs baseline: 1.1022x; 1.1022x over previous
//
#include <hip/hip_runtime.h>
#include <math.h>

#define SDE_B 16384
#define SDE_S 16
#define SDE_STEPS 50
#define SDE_L 128
#define SDE_DT 0.02f
#define SDE_SQRT_DT 0.14142135623730951f
#define SDE_TEMP 20.0f
#define LOG2E 1.44269504088896340736f
#define LN2 0.69314718055994530942f

typedef float f2 __attribute__((ext_vector_type(2)));

#if __has_builtin(__builtin_amdgcn_exp2f)
__device__ __forceinline__ float fexp2(float x) { return __builtin_amdgcn_exp2f(x); }
#else
__device__ __forceinline__ float fexp2(float x) { return __exp2f(x); }
#endif

#if __has_builtin(__builtin_amdgcn_logf)
__device__ __forceinline__ float flog2(float x) { return __builtin_amdgcn_logf(x); }
#else
__device__ __forceinline__ float flog2(float x) { return __log2f(x); }
#endif

#if __has_builtin(__builtin_amdgcn_rcpf)
__device__ __forceinline__ float frcp(float x) { return __builtin_amdgcn_rcpf(x); }
#else
__device__ __forceinline__ float frcp(float x) { return 1.0f / x; }
#endif

__device__ __forceinline__ f2 ffma2(f2 a, f2 b, f2 c) {
#if __has_builtin(__builtin_elementwise_fma)
    return __builtin_elementwise_fma(a, b, c);
#else
    return (f2){fmaf(a.x, b.x, c.x), fmaf(a.y, b.y, c.y)};
#endif
}
__device__ __forceinline__ f2 fclamp2(f2 v, float lo, float hi) {
#if __has_builtin(__builtin_elementwise_min) && __has_builtin(__builtin_elementwise_max)
    return __builtin_elementwise_min(__builtin_elementwise_max(v, (f2){lo, lo}), (f2){hi, hi});
#else
    return (f2){fminf(fmaxf(v.x, lo), hi), fminf(fmaxf(v.y, lo), hi)};
#endif
}

// stable softplus: max(y,0) + log(1+exp(-|y|))   (setup + once-per-step only)
__device__ __forceinline__ float softplus_fast(float y) {
    float m = fmaxf(y, 0.0f);
    float e = fexp2(-fabsf(y) * LOG2E);
    return fmaf(LN2, flog2(1.0f + e), m);
}

__device__ __forceinline__ float sigmoid_fast(float y) {
    return frcp(1.0f + fexp2(-y * LOG2E));
}

// sum over the 4-lane quad (lanes grouped as sim*4+q) via DPP quad_perm
__device__ __forceinline__ float quad_sum(float v) {
#if __has_builtin(__builtin_amdgcn_mov_dpp)
    int i = __float_as_int(v);
    v += __int_as_float(__builtin_amdgcn_mov_dpp(i, 0xB1, 0xF, 0xF, true)); // xor 1
    i = __float_as_int(v);
    v += __int_as_float(__builtin_amdgcn_mov_dpp(i, 0x4E, 0xF, 0xF, true)); // xor 2
    return v;
#else
    v += __shfl_xor(v, 1, 64);
    v += __shfl_xor(v, 2, 64);
    return v;
#endif
}

__device__ __forceinline__ float fixnum(float v) {
    if (isnan(v)) return 0.0f;
    if (isinf(v)) return v > 0.0f ? 3.4028234663852886e38f : -3.4028234663852886e38f;
    return v;
}

// One wave per batch element b. 64 lanes = 16 sims x 4 hidden-quarters.
// lane = s*4 + q: lane handles sim s, hidden units j = 4*i + q, i in [0,16),
// packed two-at-a-time as float2 to hit v_pk_*_f32.
// All weights + zw stay in VGPRs for the whole 50-step loop:
// __launch_bounds__(256,4) gives the register allocator a 128-VGPR budget.
__global__ void __launch_bounds__(256, 4) sde_kernel(
    const float* __restrict__ z,  const float* __restrict__ W1,
    const float* __restrict__ b1, const float* __restrict__ W2,
    const float* __restrict__ b2, const float* __restrict__ Wb,
    const float* __restrict__ bb, const float* __restrict__ Wn,
    const float* __restrict__ bn, const float* __restrict__ osc,
    const float* __restrict__ obias, const float* __restrict__ noise,
    float* __restrict__ out)
{
    __shared__ float w1s[64 * 131];   // stride 131: kills stride-130 conflicts

    for (int idx = threadIdx.x; idx < 64 * 130; idx += 256) {
        int row = idx / 130, col = idx - row * 130;
        w1s[row * 131 + col] = W1[idx];
    }
    __syncthreads();

    const int lane = threadIdx.x & 63;
    const int wv = threadIdx.x >> 6;
    const int b = blockIdx.x * 4 + wv;
    if (b >= SDE_B) return;
    const int s = lane >> 2;
    const int q = lane & 3;

    const float* zr = z + (size_t)b * SDE_L;

    // --- setup: lane `l` computes zW1 entry for hidden unit j = l ---
    float accz = b1[lane];
    #pragma unroll
    for (int m = 0; m < SDE_L; m += 4) {
        float z0 = zr[m], z1 = zr[m + 1], z2 = zr[m + 2], z3 = zr[m + 3];
        const float* wrow = &w1s[lane * 131 + 2 + m];
        accz = fmaf(z0, wrow[0], accz);
        accz = fmaf(z1, wrow[1], accz);
        accz = fmaf(z2, wrow[2], accz);
        accz = fmaf(z3, wrow[3], accz);
    }

    // --- boundary / ndt: 128-dot reduced over the wave ---
    float zb0 = zr[2 * lane], zb1 = zr[2 * lane + 1];
    float pb = fmaf(zb0, Wb[2 * lane], zb1 * Wb[2 * lane + 1]);
    float pn = fmaf(zb0, Wn[2 * lane], zb1 * Wn[2 * lane + 1]);
    #pragma unroll
    for (int off = 32; off > 0; off >>= 1) {
        pb += __shfl_xor(pb, off, 64);
        pn += __shfl_xor(pn, off, 64);
    }
    const float half_b = 0.5f * (softplus_fast(pb + bb[0]) + 0.3f);
    const float ndt = softplus_fast(pn + bn[0]) + 0.05f;

    // --- pack this lane's 16 hidden units (j = 4i+q) as 8 float2 packets,
    //     all register-resident ---
    f2 zw2[8], w1x2[8], w1t2[8], w2a2[8], w2b2[8];
    #pragma unroll
    for (int p = 0; p < 8; ++p) {
        int j0 = 4 * (2 * p) + q, j1 = 4 * (2 * p + 1) + q;
        zw2[p]  = (f2){__shfl(accz, j0, 64), __shfl(accz, j1, 64)};
        w1x2[p] = (f2){w1s[j0 * 131 + 0], w1s[j1 * 131 + 0]};
        w1t2[p] = (f2){w1s[j0 * 131 + 1], w1s[j1 * 131 + 1]};
        w2a2[p] = (f2){W2[j0], W2[j1]};
        w2b2[p] = (f2){W2[64 + j0], W2[64 + j1]};
    }

    const float b20 = b2[0], b21 = b2[1];
    const float* nzp = noise + (size_t)b * SDE_S + s;
    const f2 c105 = (f2){105.0f, 105.0f};
    const f2 c945 = (f2){945.0f, 945.0f};
    const f2 c15  = (f2){15.0f, 15.0f};
    const f2 c420 = (f2){420.0f, 420.0f};

    float x = 0.0f, surv = 1.0f, ert = 0.0f, ecorr = 0.0f;
    float nz = nzp[0];

    for (int k = 0; k < SDE_STEPS; ++k) {
        // prefetch next step's noise (clamped index, branchless)
        int kn = (k + 1 < SDE_STEPS) ? k + 1 : k;
        float nz_next = nzp[(size_t)kn * (SDE_B * SDE_S)];

        float t = (float)k * SDE_DT;
        f2 x2 = (f2){x, x}, t2 = (f2){t, t};
        f2 A0 = (f2){0.0f, 0.0f}, A1 = (f2){0.0f, 0.0f};
        #pragma unroll
        for (int g = 0; g < 4; ++g) {
            f2 pre0 = ffma2(x2, w1x2[2 * g],     ffma2(t2, w1t2[2 * g],     zw2[2 * g]));
            f2 pre1 = ffma2(x2, w1x2[2 * g + 1], ffma2(t2, w1t2[2 * g + 1], zw2[2 * g + 1]));
            // Pade [5/4] tanh, input clamped to +-3.8 (max err ~1.4e-3)
            pre0 = fclamp2(pre0, -3.8f, 3.8f);
            pre1 = fclamp2(pre1, -3.8f, 3.8f);
            f2 tt0 = pre0 * pre0, tt1 = pre1 * pre1;
            f2 num0 = pre0 * ffma2(tt0, tt0 + c105, c945);
            f2 num1 = pre1 * ffma2(tt1, tt1 + c105, c945);
            f2 den0 = ffma2(tt0, ffma2(tt0, c15, c420), c945);
            f2 den1 = ffma2(tt1, ffma2(tt1, c15, c420), c945);
            // one rcp serves 4 divisions
            float d0 = den0.x, d1 = den0.y, d2 = den1.x, d3 = den1.y;
            float p01 = d0 * d1, p23 = d2 * d3;
            float r = frcp(p01 * p23);
            float r01 = r * p23, r23 = r * p01;
            f2 h0 = num0 * (f2){r01 * d1, r01 * d0};
            f2 h1 = num1 * (f2){r23 * d3, r23 * d2};
            A0 = ffma2(h0, w2a2[2 * g], A0);
            A0 = ffma2(h1, w2a2[2 * g + 1], A0);
            A1 = ffma2(h0, w2b2[2 * g], A1);
            A1 = ffma2(h1, w2b2[2 * g + 1], A1);
        }
        float a0 = A0.x + A0.y;
        float a1 = A1.x + A1.y;
        a0 = quad_sum(a0);
        a1 = quad_sum(a1);
        // identical on all 4 lanes of the quad -> state stays consistent
        float drift = fminf(fmaxf(a0 + b20, -5.0f), 5.0f);
        float diff = softplus_fast(a1 + b21) + 0.1f;
        x = fmaf(drift, SDE_DT, fmaf(diff * SDE_SQRT_DT, nz, x));
        x = fminf(fmaxf(x, -10.0f), 10.0f);
        float dist = fabsf(x) - half_b;
        float hz = fminf(sigmoid_fast(SDE_TEMP * dist), 0.99f);
        float cross = surv * hz;
        surv = surv * (1.0f - hz);      // == exp(sum log1p(-hz)) to fp32 rounding
        float tn = (float)(k + 1) * SDE_DT;
        ert = fmaf(cross, tn, ert);
        ecorr += (x > 0.0f) ? cross : 0.0f;
        nz = nz_next;
    }

    ert += surv;                    // * (STEPS*DT) = 1.0
    ecorr = fmaf(surv, 0.5f, ecorr);
    float rt = ert + ndt;           // seconds; x1000 applied after stats

    // --- stats over 16 sims (mask quad-redundant copies to q==0) ---
    float sr = (q == 0) ? rt : 0.0f;
    float scr = (q == 0) ? ecorr : 0.0f;
    #pragma unroll
    for (int off = 32; off > 0; off >>= 1) {
        sr += __shfl_xor(sr, off, 64);
        scr += __shfl_xor(scr, off, 64);
    }
    float mean = sr * (1.0f / 16.0f);
    float d = rt - mean;
    float vv = (q == 0) ? d * d : 0.0f;
    #pragma unroll
    for (int off = 32; off > 0; off >>= 1) vv += __shfl_xor(vv, off, 64);

    if (lane == 0) {
        float std_ms = sqrtf(vv * (1.0f / 15.0f)) * 1000.0f + 0.001f;
        float o0 = fmaf(mean * 1000.0f, osc[0], obias[0]);
        float o1 = fmaf(std_ms, osc[1], obias[1]);
        float o2 = fmaf(scr * (1.0f / 16.0f), osc[2], obias[2]);
        out[b * 3 + 0] = fixnum(o0);
        out[b * 3 + 1] = fixnum(o1);
        out[b * 3 + 2] = fixnum(o2);
    }
}

extern "C" void kernel_launch(void* const* d_in, const int* in_sizes, int n_in,
                              void* d_out, int out_size, void* d_ws, size_t ws_size,
                              hipStream_t stream) {
    const float* z     = (const float*)d_in[0];
    const float* W1    = (const float*)d_in[1];
    const float* b1    = (const float*)d_in[2];
    const float* W2    = (const float*)d_in[3];
    const float* b2    = (const float*)d_in[4];
    const float* Wb    = (const float*)d_in[5];
    const float* bb    = (const float*)d_in[6];
    const float* Wn    = (const float*)d_in[7];
    const float* bn    = (const float*)d_in[8];
    const float* osc   = (const float*)d_in[9];
    const float* obias = (const float*)d_in[10];
    const float* noise = (const float*)d_in[11];
    float* out = (float*)d_out;

    dim3 grid(SDE_B / 4), block(256);
    sde_kernel<<<grid, block, 0, stream>>>(z, W1, b1, W2, b2, Wb, bb, Wn, bn,
                                           osc, obias, noise, out);
}